// Round 4
// baseline (174.659 us; speedup 1.0000x reference)
//
#include <hip/hip_runtime.h>
#include <hip/hip_bf16.h>

typedef __attribute__((ext_vector_type(8))) short bf16x8;
typedef __attribute__((ext_vector_type(4))) float f32x4;
typedef __attribute__((ext_vector_type(16))) float f32x16;

__device__ __forceinline__ void gload_lds16(const void* g, void* l) {
    __builtin_amdgcn_global_load_lds(
        (const __attribute__((address_space(1))) unsigned int*)g,
        (__attribute__((address_space(3))) unsigned int*)l, 16, 0, 0);
}

__device__ __forceinline__ unsigned int pk2(float x, float y) {
    union { __hip_bfloat16 h[2]; unsigned int u; } z;
    z.h[0] = __float2bfloat16(x); z.h[1] = __float2bfloat16(y);
    return z.u;
}

// ---------------- fp32 -> bf16 elementwise convert (8 elems/thread) ----------------
__global__ void k_cvt_bf16(const float* __restrict__ x, __hip_bfloat16* __restrict__ o, int n8) {
    int i = blockIdx.x * 256 + threadIdx.x;
    if (i >= n8) return;
    const float4* xp = (const float4*)(x + (size_t)i * 8);
    float4 a = xp[0], b = xp[1];
    union { __hip_bfloat16 h[8]; uint4 u; } tu;
    tu.h[0] = __float2bfloat16(a.x); tu.h[1] = __float2bfloat16(a.y);
    tu.h[2] = __float2bfloat16(a.z); tu.h[3] = __float2bfloat16(a.w);
    tu.h[4] = __float2bfloat16(b.x); tu.h[5] = __float2bfloat16(b.y);
    tu.h[6] = __float2bfloat16(b.z); tu.h[7] = __float2bfloat16(b.w);
    *(uint4*)(o + (size_t)i * 8) = tu.u;
}

// ---------------- transpose fp32 [K][N] -> bf16 [N][K] ----------------
__global__ void k_tr(const float* __restrict__ src, __hip_bfloat16* __restrict__ dst, int K, int N) {
    __shared__ float tile[32][33];
    int n0 = blockIdx.x * 32, k0 = blockIdx.y * 32;
    int tx = threadIdx.x & 31, ty = threadIdx.x >> 5;
#pragma unroll
    for (int i = 0; i < 4; i++)
        tile[ty + i * 8][tx] = src[(size_t)(k0 + ty + i * 8) * N + n0 + tx];
    __syncthreads();
#pragma unroll
    for (int i = 0; i < 4; i++)
        dst[(size_t)(n0 + ty + i * 8) * K + k0 + tx] = __float2bfloat16(tile[tx][ty + i * 8]);
}

// ---------------- bf16 GEMM: C[M][N] = A[M][K] * Bt[N][K]^T, 128x128 tile ----------------
// T3-minimum pipeline: double-buffered LDS, prefetch tile t+1 before computing tile t.
#define QSCALE 0.18033688011111204f  /* (1/8) * log2(e) */

template <int EPI>
__global__ __launch_bounds__(256, 2) void k_gemm(
    const __hip_bfloat16* __restrict__ A, const __hip_bfloat16* __restrict__ Bt,
    int M, int N, int K,
    const float* __restrict__ b0, const float* __restrict__ b1, const float* __restrict__ b2,
    __hip_bfloat16* __restrict__ qb, __hip_bfloat16* __restrict__ kb, __hip_bfloat16* __restrict__ vb,
    float* __restrict__ outp)
{
    __shared__ __align__(16) __hip_bfloat16 As[2][128 * 64];
    __shared__ __align__(16) __hip_bfloat16 Bs[2][128 * 64];
    const int t = threadIdx.x;
    const int lane = t & 63, w = t >> 6;
    const int wr = w >> 1, wc = w & 1;
    const int r16 = lane & 15, kg = lane >> 4;
    const int m0 = blockIdx.x * 128, n0 = blockIdx.y * 128;
    f32x4 acc[4][4] = {};
    const int ksteps = K >> 6;

    auto stage = [&](int buf, int kt) {
        const int ks = kt * 64;
#pragma unroll
        for (int i = 0; i < 4; i++) {
            int ci = i * 256 + t;
            int row = ci >> 3, kc = (ci & 7) * 8;
            gload_lds16(A + (size_t)(m0 + row) * K + ks + kc, &As[buf][ci * 8]);
        }
#pragma unroll
        for (int i = 0; i < 4; i++) {
            int ci = i * 256 + t;
            int row = ci >> 3, kc = (ci & 7) * 8;
            gload_lds16(Bt + (size_t)(n0 + row) * K + ks + kc, &Bs[buf][ci * 8]);
        }
    };

    stage(0, 0);
    __syncthreads();
    int cur = 0;
    for (int kt = 0; kt < ksteps; ++kt) {
        if (kt + 1 < ksteps) stage(cur ^ 1, kt + 1);  // in-flight during this tile's compute
#pragma unroll
        for (int c = 0; c < 2; c++) {
            bf16x8 af[4], bfr[4];
#pragma unroll
            for (int mi = 0; mi < 4; mi++)
                af[mi] = *(const bf16x8*)(&As[cur][(wr * 64 + mi * 16 + r16) * 64 + c * 32 + kg * 8]);
#pragma unroll
            for (int ni = 0; ni < 4; ni++)
                bfr[ni] = *(const bf16x8*)(&Bs[cur][(wc * 64 + ni * 16 + r16) * 64 + c * 32 + kg * 8]);
#pragma unroll
            for (int mi = 0; mi < 4; mi++)
#pragma unroll
                for (int ni = 0; ni < 4; ni++)
                    acc[mi][ni] = __builtin_amdgcn_mfma_f32_16x16x32_bf16(af[mi], bfr[ni], acc[mi][ni], 0, 0, 0);
        }
        __syncthreads();  // drains vmcnt(0): prefetched tile landed; cur buffer free next iter
        cur ^= 1;
    }
#pragma unroll
    for (int mi = 0; mi < 4; mi++) {
#pragma unroll
        for (int ni = 0; ni < 4; ni++) {
#pragma unroll
            for (int j = 0; j < 4; j++) {
                int m = m0 + wr * 64 + mi * 16 + kg * 4 + j;
                int n = n0 + wc * 64 + ni * 16 + r16;
                float val = acc[mi][ni][j];
                if (EPI == 0) {
                    int proj = n >> 10, r = n & 1023;
                    int hh = r >> 6, dd = r & 63;
                    int bb = m >> 11, tt = m & 2047;
                    if (proj == 0) {
                        val = (val + b0[r]) * QSCALE;
                        qb[((size_t)(bb * 16 + hh) * 2048 + tt) * 64 + dd] = __float2bfloat16(val);
                    } else if (proj == 1) {
                        val += b1[r];
                        kb[((size_t)(bb * 16 + hh) * 2048 + tt) * 64 + dd] = __float2bfloat16(val);
                    } else {
                        val += b2[r];
                        vb[((size_t)(bb * 16 + hh) * 64 + dd) * 2048 + tt] = __float2bfloat16(val);
                    }
                } else {
                    outp[(size_t)m * N + n] = val + b0[n];
                }
            }
        }
    }
}

// ---------------- flash attention v4: 32x32 MFMA, fully in-register softmax ----------------
// - swapped QK^T (mfma(K,Q)): C col = lane&31 = q  -> m/l lane-local, row reduce = 31 fmax + 1 shfl_xor(32)
// - P assembled in-register (pack bf16 pairs + shfl_xor(32) half-exchange) -> NO LDS roundtrip
// - each wave owns 32 q-rows, block = 128 q-rows; KVBLK=64, double-buffered K/V via global_load_lds
// - balanced remap: co-resident pair (qt, 15-qt) -> uniform 34 iters/CU
__global__ __launch_bounds__(256, 2) void k_attn(
    const __hip_bfloat16* __restrict__ qbuf,
    const __hip_bfloat16* __restrict__ kbuf,
    const __hip_bfloat16* __restrict__ vtbuf,
    __hip_bfloat16* __restrict__ y)
{
    __shared__ __align__(16) __hip_bfloat16 Kl[2][64 * 64];
    __shared__ __align__(16) __hip_bfloat16 Vl[2][64 * 64];
    const int t = threadIdx.x, lane = t & 63, w = t >> 6;
    const int l31 = lane & 31, hi = lane >> 5;
    const int g = blockIdx.x;
    const int c2 = g >> 8, p = g & 255;
    const int bh = p & 31;
    const int rr = p >> 5;
    const int qt = c2 ? (15 - rr) : rr;
    const int nt = 2 * qt + 2;
    const int q0w = qt * 128 + w * 32;
    const int swr = (l31 & 7) << 3;  // read-side XOR swizzle (elements); same for rows l31 and 32+l31

    const __hip_bfloat16* qp = qbuf + ((size_t)bh * 2048 + q0w + l31) * 64;
    bf16x8 qf[4];
#pragma unroll
    for (int dt = 0; dt < 4; dt++)
        qf[dt] = *(const bf16x8*)(qp + dt * 16 + hi * 8);

    f32x16 O0 = {}, O1 = {};
    float m_s = -3.0e38f, l_s = 0.f;
    const __hip_bfloat16* kb = kbuf + (size_t)bh * 2048 * 64;
    const __hip_bfloat16* vb = vtbuf + (size_t)bh * 64 * 2048;

    const int ci0 = t, ci1 = 256 + t;
    const int kr0 = ci0 >> 3, sc0 = ((ci0 & 7) * 8) ^ ((kr0 & 7) << 3);
    const int kr1 = ci1 >> 3, sc1 = ((ci1 & 7) * 8) ^ ((kr1 & 7) << 3);

    // prologue: stage tile 0 into buffer 0 (pre-swizzled global source, linear LDS dest)
    gload_lds16(kb + (size_t)kr0 * 64 + sc0, &Kl[0][ci0 * 8]);
    gload_lds16(kb + (size_t)kr1 * 64 + sc1, &Kl[0][ci1 * 8]);
    gload_lds16(vb + (size_t)kr0 * 2048 + sc0, &Vl[0][ci0 * 8]);
    gload_lds16(vb + (size_t)kr1 * 2048 + sc1, &Vl[0][ci1 * 8]);
    __syncthreads();

    for (int kt = 0; kt < nt; ++kt) {
        const int cur = kt & 1;
        if (kt + 1 < nt) {  // prefetch next tile; overlaps this tile's compute
            const int kn = kt + 1;
            gload_lds16(kb + (size_t)kn * 4096 + (size_t)kr0 * 64 + sc0, &Kl[cur ^ 1][ci0 * 8]);
            gload_lds16(kb + (size_t)kn * 4096 + (size_t)kr1 * 64 + sc1, &Kl[cur ^ 1][ci1 * 8]);
            gload_lds16(vb + (size_t)kr0 * 2048 + kn * 64 + sc0, &Vl[cur ^ 1][ci0 * 8]);
            gload_lds16(vb + (size_t)kr1 * 2048 + kn * 64 + sc1, &Vl[cur ^ 1][ci1 * 8]);
        }
        const int kbase = kt * 64;
        if (kbase <= q0w + 31) {  // wave-uniform activity gate
            const __hip_bfloat16* Klb = Kl[cur];
            const __hip_bfloat16* Vlb = Vl[cur];
            // QK^T swapped: S^T[k][q]; lane: q = l31, k rows = (r&3)+8*(r>>2)+4*hi (+32 for s1)
            f32x16 s0 = {}, s1 = {};
#pragma unroll
            for (int dt = 0; dt < 4; dt++) {
                bf16x8 ka = *(const bf16x8*)(Klb + l31 * 64 + ((dt * 16 + hi * 8) ^ swr));
                s0 = __builtin_amdgcn_mfma_f32_32x32x16_bf16(ka, qf[dt], s0, 0, 0, 0);
            }
#pragma unroll
            for (int dt = 0; dt < 4; dt++) {
                bf16x8 kb2 = *(const bf16x8*)(Klb + (32 + l31) * 64 + ((dt * 16 + hi * 8) ^ swr));
                s1 = __builtin_amdgcn_mfma_f32_32x32x16_bf16(kb2, qf[dt], s1, 0, 0, 0);
            }
            if (kbase + 63 > q0w) {  // causal mask (partial-overlap tiles only)
                const int qg = q0w + l31;
#pragma unroll
                for (int r = 0; r < 16; ++r) {
                    const int krow = (r & 3) + 8 * (r >> 2) + 4 * hi;
                    if (kbase + krow > qg) s0[r] = -3.0e38f;
                    if (kbase + 32 + krow > qg) s1[r] = -3.0e38f;
                }
            }
            float rmax = s0[0];
#pragma unroll
            for (int r = 1; r < 16; ++r) rmax = fmaxf(rmax, s0[r]);
#pragma unroll
            for (int r = 0; r < 16; ++r) rmax = fmaxf(rmax, s1[r]);
            rmax = fmaxf(rmax, __shfl_xor(rmax, 32));
            // defer-max (T13, THR=8)
            if (__any(rmax > m_s + 8.0f)) {
                const float mn = fmaxf(m_s, rmax);
                const float al = exp2f(m_s - mn);
                m_s = mn;
                l_s *= al;
#pragma unroll
                for (int r = 0; r < 16; ++r) {
                    const int qrow = (r & 3) + 8 * (r >> 2) + 4 * hi;
                    const float ar = __shfl(al, qrow);
                    O0[r] *= ar; O1[r] *= ar;
                }
            }
            float rsum = 0.f;
#pragma unroll
            for (int r = 0; r < 16; ++r) { s0[r] = exp2f(s0[r] - m_s); rsum += s0[r]; }
#pragma unroll
            for (int r = 0; r < 16; ++r) { s1[r] = exp2f(s1[r] - m_s); rsum += s1[r]; }
            rsum += __shfl_xor(rsum, 32);
            l_s += rsum;
            // P -> PV A-frags fully in-register (pack pairs, exchange halves via shfl_xor 32)
            bf16x8 pa[4];
#pragma unroll
            for (int kt4 = 0; kt4 < 4; ++kt4) {
                const f32x16& sc = (kt4 < 2) ? s0 : s1;
                const int a8 = (kt4 & 1) * 8;
                const unsigned int plo0 = pk2(sc[a8 + 0], sc[a8 + 1]);
                const unsigned int plo1 = pk2(sc[a8 + 2], sc[a8 + 3]);
                const unsigned int phi0 = pk2(sc[a8 + 4], sc[a8 + 5]);
                const unsigned int phi1 = pk2(sc[a8 + 6], sc[a8 + 7]);
                const unsigned int snd0 = hi ? plo0 : phi0;
                const unsigned int snd1 = hi ? plo1 : phi1;
                const unsigned int r0 = (unsigned int)__shfl_xor((int)snd0, 32);
                const unsigned int r1 = (unsigned int)__shfl_xor((int)snd1, 32);
                union { unsigned int u[4]; bf16x8 v; } fr;
                fr.u[0] = hi ? r0 : plo0;
                fr.u[1] = hi ? r1 : plo1;
                fr.u[2] = hi ? phi0 : r0;
                fr.u[3] = hi ? phi1 : r1;
                pa[kt4] = fr.v;
            }
            // PV: A = P[32q x 16k], B = V[16k x 32d] from V^T LDS rows d
#pragma unroll
            for (int kt4 = 0; kt4 < 4; ++kt4) {
                bf16x8 vf0 = *(const bf16x8*)(Vlb + l31 * 64 + ((kt4 * 16 + hi * 8) ^ swr));
                O0 = __builtin_amdgcn_mfma_f32_32x32x16_bf16(pa[kt4], vf0, O0, 0, 0, 0);
                bf16x8 vf1 = *(const bf16x8*)(Vlb + (32 + l31) * 64 + ((kt4 * 16 + hi * 8) ^ swr));
                O1 = __builtin_amdgcn_mfma_f32_32x32x16_bf16(pa[kt4], vf1, O1, 0, 0, 0);
            }
        }
        __syncthreads();  // drains vmcnt(0): next buffer staged; cur buffer free
    }
    const int b = bh >> 4, h = bh & 15;
    const float linv = 1.0f / l_s;
#pragma unroll
    for (int r = 0; r < 16; ++r) {
        const int qrow = (r & 3) + 8 * (r >> 2) + 4 * hi;
        const float iv = __shfl(linv, qrow);
        const size_t ro = ((size_t)b * 2048 + q0w + qrow) * 1024 + (size_t)h * 64;
        y[ro + l31] = __float2bfloat16(O0[r] * iv);
        y[ro + 32 + l31] = __float2bfloat16(O1[r] * iv);
    }
}

extern "C" void kernel_launch(void* const* d_in, const int* in_sizes, int n_in,
                              void* d_out, int out_size, void* d_ws, size_t ws_size,
                              hipStream_t stream) {
    const float* xp = (const float*)d_in[0];
    const float* Wq = (const float*)d_in[1];
    const float* bq = (const float*)d_in[2];
    const float* Wk = (const float*)d_in[3];
    const float* bk = (const float*)d_in[4];
    const float* Wv = (const float*)d_in[5];
    const float* bv = (const float*)d_in[6];
    const float* Wp = (const float*)d_in[7];
    const float* bp = (const float*)d_in[8];
    float* out = (float*)d_out;

    char* ws = (char*)d_ws;
    __hip_bfloat16* xb     = (__hip_bfloat16*)(ws);                  //  4096*1152 bf16
    __hip_bfloat16* Wqkv_t = (__hip_bfloat16*)(ws + 9437184);        //  3072*1152 bf16 (B^T)
    __hip_bfloat16* Wp_t   = (__hip_bfloat16*)(ws + 16515072);       //  1024*1024 bf16 (B^T)
    __hip_bfloat16* qb     = (__hip_bfloat16*)(ws + 18612224);       //  [32][2048][64]
    __hip_bfloat16* kbv    = (__hip_bfloat16*)(ws + 27000832);       //  [32][2048][64]
    __hip_bfloat16* vtb    = (__hip_bfloat16*)(ws + 35389440);       //  [32][64][2048] (V^T)
    __hip_bfloat16* yb     = (__hip_bfloat16*)(ws + 43778048);       //  [4096][1024]

    k_cvt_bf16<<<2304, 256, 0, stream>>>(xp, xb, 589824);
    dim3 trg(1024 / 32, 1152 / 32);
    k_tr<<<trg, 256, 0, stream>>>(Wq, Wqkv_t + (size_t)0 * 1024 * 1152, 1152, 1024);
    k_tr<<<trg, 256, 0, stream>>>(Wk, Wqkv_t + (size_t)1 * 1024 * 1152, 1152, 1024);
    k_tr<<<trg, 256, 0, stream>>>(Wv, Wqkv_t + (size_t)2 * 1024 * 1152, 1152, 1024);
    dim3 trg2(1024 / 32, 1024 / 32);
    k_tr<<<trg2, 256, 0, stream>>>(Wp, Wp_t, 1024, 1024);

    dim3 g1(4096 / 128, 3072 / 128);
    k_gemm<0><<<g1, 256, 0, stream>>>(xb, Wqkv_t, 4096, 3072, 1152, bq, bk, bv, qb, kbv, vtb, nullptr);
    k_attn<<<512, 256, 0, stream>>>(qb, kbv, vtb, yb);
    dim3 g2(4096 / 128, 1024 / 128);
    k_gemm<1><<<g2, 256, 0, stream>>>(yb, Wp_t, 4096, 1024, 1024, bp, nullptr, nullptr,
                                      nullptr, nullptr, nullptr, out);
}

// Round 5
// 151.007 us; speedup vs baseline: 1.1566x; 1.1566x over previous
//
#include <hip/hip_runtime.h>
#include <hip/hip_bf16.h>

typedef __attribute__((ext_vector_type(8))) short bf16x8;
typedef __attribute__((ext_vector_type(4))) float f32x4;
typedef __attribute__((ext_vector_type(16))) float f32x16;

__device__ __forceinline__ void gload_lds16(const void* g, void* l) {
    __builtin_amdgcn_global_load_lds(
        (const __attribute__((address_space(1))) unsigned int*)g,
        (__attribute__((address_space(3))) unsigned int*)l, 16, 0, 0);
}

__device__ __forceinline__ unsigned int pk2(float x, float y) {
    union { __hip_bfloat16 h[2]; unsigned int u; } z;
    z.h[0] = __float2bfloat16(x); z.h[1] = __float2bfloat16(y);
    return z.u;
}

// ---------------- fp32 -> bf16 elementwise convert (8 elems/thread) ----------------
__global__ void k_cvt_bf16(const float* __restrict__ x, __hip_bfloat16* __restrict__ o, int n8) {
    int i = blockIdx.x * 256 + threadIdx.x;
    if (i >= n8) return;
    const float4* xp = (const float4*)(x + (size_t)i * 8);
    float4 a = xp[0], b = xp[1];
    union { __hip_bfloat16 h[8]; uint4 u; } tu;
    tu.h[0] = __float2bfloat16(a.x); tu.h[1] = __float2bfloat16(a.y);
    tu.h[2] = __float2bfloat16(a.z); tu.h[3] = __float2bfloat16(a.w);
    tu.h[4] = __float2bfloat16(b.x); tu.h[5] = __float2bfloat16(b.y);
    tu.h[6] = __float2bfloat16(b.z); tu.h[7] = __float2bfloat16(b.w);
    *(uint4*)(o + (size_t)i * 8) = tu.u;
}

// ---------------- transpose fp32 [K][N] -> bf16 [N][K]; z selects one of 3 sources ----------------
__global__ void k_tr3(const float* __restrict__ s0, const float* __restrict__ s1,
                      const float* __restrict__ s2, __hip_bfloat16* __restrict__ dst,
                      int K, int N) {
    __shared__ float tile[32][33];
    const float* src = (blockIdx.z == 0) ? s0 : ((blockIdx.z == 1) ? s1 : s2);
    __hip_bfloat16* d = dst + (size_t)blockIdx.z * N * K;
    int n0 = blockIdx.x * 32, k0 = blockIdx.y * 32;
    int tx = threadIdx.x & 31, ty = threadIdx.x >> 5;
#pragma unroll
    for (int i = 0; i < 4; i++)
        tile[ty + i * 8][tx] = src[(size_t)(k0 + ty + i * 8) * N + n0 + tx];
    __syncthreads();
#pragma unroll
    for (int i = 0; i < 4; i++)
        d[(size_t)(n0 + ty + i * 8) * K + k0 + tx] = __float2bfloat16(tile[tx][ty + i * 8]);
}

__global__ void k_tr(const float* __restrict__ src, __hip_bfloat16* __restrict__ dst, int K, int N) {
    __shared__ float tile[32][33];
    int n0 = blockIdx.x * 32, k0 = blockIdx.y * 32;
    int tx = threadIdx.x & 31, ty = threadIdx.x >> 5;
#pragma unroll
    for (int i = 0; i < 4; i++)
        tile[ty + i * 8][tx] = src[(size_t)(k0 + ty + i * 8) * N + n0 + tx];
    __syncthreads();
#pragma unroll
    for (int i = 0; i < 4; i++)
        dst[(size_t)(n0 + ty + i * 8) * K + k0 + tx] = __float2bfloat16(tile[tx][ty + i * 8]);
}

// ---------------- bf16 GEMM (round-3 proven): C = A * Bt^T, 128x128 tile, 32KB LDS ----------------
#define QSCALE 0.18033688011111204f  /* (1/8) * log2(e) */

template <int EPI>
__global__ __launch_bounds__(256, 2) void k_gemm(
    const __hip_bfloat16* __restrict__ A, const __hip_bfloat16* __restrict__ Bt,
    int M, int N, int K,
    const float* __restrict__ b0, const float* __restrict__ b1, const float* __restrict__ b2,
    __hip_bfloat16* __restrict__ qb, __hip_bfloat16* __restrict__ kb, __hip_bfloat16* __restrict__ vb,
    float* __restrict__ outp)
{
    __shared__ __align__(16) __hip_bfloat16 As[128 * 64];
    __shared__ __align__(16) __hip_bfloat16 Bs[128 * 64];
    const int t = threadIdx.x;
    const int lane = t & 63, w = t >> 6;
    const int wr = w >> 1, wc = w & 1;
    const int r16 = lane & 15, kg = lane >> 4;
    const int m0 = blockIdx.x * 128, n0 = blockIdx.y * 128;
    f32x4 acc[4][4] = {};
    const int ksteps = K >> 6;
    for (int kt = 0; kt < ksteps; ++kt) {
        if (kt) __syncthreads();
        const int ks = kt * 64;
#pragma unroll
        for (int i = 0; i < 4; i++) {
            int ci = i * 256 + t;
            int row = ci >> 3, kc = (ci & 7) * 8;
            gload_lds16(A + (size_t)(m0 + row) * K + ks + kc, As + ci * 8);
        }
#pragma unroll
        for (int i = 0; i < 4; i++) {
            int ci = i * 256 + t;
            int row = ci >> 3, kc = (ci & 7) * 8;
            gload_lds16(Bt + (size_t)(n0 + row) * K + ks + kc, Bs + ci * 8);
        }
        __syncthreads();
#pragma unroll
        for (int c = 0; c < 2; c++) {
            bf16x8 af[4], bfr[4];
#pragma unroll
            for (int mi = 0; mi < 4; mi++)
                af[mi] = *(const bf16x8*)(As + (wr * 64 + mi * 16 + r16) * 64 + c * 32 + kg * 8);
#pragma unroll
            for (int ni = 0; ni < 4; ni++)
                bfr[ni] = *(const bf16x8*)(Bs + (wc * 64 + ni * 16 + r16) * 64 + c * 32 + kg * 8);
#pragma unroll
            for (int mi = 0; mi < 4; mi++)
#pragma unroll
                for (int ni = 0; ni < 4; ni++)
                    acc[mi][ni] = __builtin_amdgcn_mfma_f32_16x16x32_bf16(af[mi], bfr[ni], acc[mi][ni], 0, 0, 0);
        }
    }
#pragma unroll
    for (int mi = 0; mi < 4; mi++) {
#pragma unroll
        for (int ni = 0; ni < 4; ni++) {
#pragma unroll
            for (int j = 0; j < 4; j++) {
                int m = m0 + wr * 64 + mi * 16 + kg * 4 + j;
                int n = n0 + wc * 64 + ni * 16 + r16;
                float val = acc[mi][ni][j];
                if (EPI == 0) {
                    int proj = n >> 10, r = n & 1023;
                    int hh = r >> 6, dd = r & 63;
                    int bb = m >> 11, tt = m & 2047;
                    if (proj == 0) {
                        val = (val + b0[r]) * QSCALE;
                        qb[((size_t)(bb * 16 + hh) * 2048 + tt) * 64 + dd] = __float2bfloat16(val);
                    } else if (proj == 1) {
                        val += b1[r];
                        kb[((size_t)(bb * 16 + hh) * 2048 + tt) * 64 + dd] = __float2bfloat16(val);
                    } else {
                        val += b2[r];
                        vb[((size_t)(bb * 16 + hh) * 64 + dd) * 2048 + tt] = __float2bfloat16(val);
                    }
                } else {
                    outp[(size_t)m * N + n] = val + b0[n];
                }
            }
        }
    }
}

// ---------------- flash attention v5: v4 compute + 3-buffer 2-ahead counted-vmcnt pipeline ----------
// Key fix vs v2-v4: __syncthreads() drains vmcnt(0) (waits the just-issued prefetch every iter).
// Replaced by: per-wave s_waitcnt vmcnt(4) (this tile's 4 loads done, next tile's 4 stay in
// flight) + raw s_barrier + sched_barrier(0). Loads issued 2 tiles ahead into buf[kt%3].
// Write-after-read: tile t+2 -> buf[(t-1)%3], whose readers all passed this iter's barrier.
__global__ __launch_bounds__(256, 2) void k_attn(
    const __hip_bfloat16* __restrict__ qbuf,
    const __hip_bfloat16* __restrict__ kbuf,
    const __hip_bfloat16* __restrict__ vtbuf,
    __hip_bfloat16* __restrict__ y)
{
    __shared__ __align__(16) __hip_bfloat16 Kl[3][64 * 64];
    __shared__ __align__(16) __hip_bfloat16 Vl[3][64 * 64];
    const int t = threadIdx.x, lane = t & 63, w = t >> 6;
    const int l31 = lane & 31, hi = lane >> 5;
    const int g = blockIdx.x;
    const int c2 = g >> 8, p = g & 255;
    const int bh = p & 31;
    const int rr = p >> 5;
    const int qt = c2 ? (15 - rr) : rr;
    const int nt = 2 * qt + 2;
    const int q0w = qt * 128 + w * 32;
    const int swr = (l31 & 7) << 3;  // read-side XOR swizzle (elements)

    const __hip_bfloat16* qp = qbuf + ((size_t)bh * 2048 + q0w + l31) * 64;
    bf16x8 qf[4];
#pragma unroll
    for (int dt = 0; dt < 4; dt++)
        qf[dt] = *(const bf16x8*)(qp + dt * 16 + hi * 8);

    f32x16 O0 = {}, O1 = {};
    float m_s = -3.0e38f, l_s = 0.f;
    const __hip_bfloat16* kb = kbuf + (size_t)bh * 2048 * 64;
    const __hip_bfloat16* vb = vtbuf + (size_t)bh * 64 * 2048;

    const int ci0 = t, ci1 = 256 + t;
    const int kr0 = ci0 >> 3, sc0 = ((ci0 & 7) * 8) ^ ((kr0 & 7) << 3);
    const int kr1 = ci1 >> 3, sc1 = ((ci1 & 7) * 8) ^ ((kr1 & 7) << 3);

    // prologue: issue tiles 0 and 1 (nt >= 2 always); 8 vmem ops outstanding per wave
#pragma unroll
    for (int pt = 0; pt < 2; ++pt) {
        gload_lds16(kb + (size_t)pt * 4096 + (size_t)kr0 * 64 + sc0, &Kl[pt][ci0 * 8]);
        gload_lds16(kb + (size_t)pt * 4096 + (size_t)kr1 * 64 + sc1, &Kl[pt][ci1 * 8]);
        gload_lds16(vb + (size_t)kr0 * 2048 + pt * 64 + sc0, &Vl[pt][ci0 * 8]);
        gload_lds16(vb + (size_t)kr1 * 2048 + pt * 64 + sc1, &Vl[pt][ci1 * 8]);
    }

    for (int kt = 0; kt < nt; ++kt) {
        // wait own tile-kt loads only; tile kt+1's 4 loads remain in flight
        if (kt < nt - 1) {
            asm volatile("s_waitcnt vmcnt(4)" ::: "memory");
        } else {
            asm volatile("s_waitcnt vmcnt(0)" ::: "memory");
        }
        __builtin_amdgcn_s_barrier();          // raw barrier: NO implicit vmcnt drain
        __builtin_amdgcn_sched_barrier(0);     // rule #18: pin reads below the wait
        if (kt + 2 < nt) {                     // issue tile kt+2 into buf[(kt+2)%3]
            const int kn = kt + 2;
            const int nb = kn % 3;
            gload_lds16(kb + (size_t)kn * 4096 + (size_t)kr0 * 64 + sc0, &Kl[nb][ci0 * 8]);
            gload_lds16(kb + (size_t)kn * 4096 + (size_t)kr1 * 64 + sc1, &Kl[nb][ci1 * 8]);
            gload_lds16(vb + (size_t)kr0 * 2048 + kn * 64 + sc0, &Vl[nb][ci0 * 8]);
            gload_lds16(vb + (size_t)kr1 * 2048 + kn * 64 + sc1, &Vl[nb][ci1 * 8]);
        }
        const int cb = kt % 3;
        const int kbase = kt * 64;
        if (kbase <= q0w + 31) {  // wave-uniform activity gate
            const __hip_bfloat16* Klb = Kl[cb];
            const __hip_bfloat16* Vlb = Vl[cb];
            // swapped QK^T: S^T[k][q]; lane: q = l31, k rows = (r&3)+8*(r>>2)+4*hi (+32 for s1)
            f32x16 s0 = {}, s1 = {};
#pragma unroll
            for (int dt = 0; dt < 4; dt++) {
                bf16x8 ka = *(const bf16x8*)(Klb + l31 * 64 + ((dt * 16 + hi * 8) ^ swr));
                s0 = __builtin_amdgcn_mfma_f32_32x32x16_bf16(ka, qf[dt], s0, 0, 0, 0);
            }
#pragma unroll
            for (int dt = 0; dt < 4; dt++) {
                bf16x8 kb2 = *(const bf16x8*)(Klb + (32 + l31) * 64 + ((dt * 16 + hi * 8) ^ swr));
                s1 = __builtin_amdgcn_mfma_f32_32x32x16_bf16(kb2, qf[dt], s1, 0, 0, 0);
            }
            if (kbase + 63 > q0w) {  // causal mask (partial-overlap tiles only)
                const int qg = q0w + l31;
#pragma unroll
                for (int r = 0; r < 16; ++r) {
                    const int krow = (r & 3) + 8 * (r >> 2) + 4 * hi;
                    if (kbase + krow > qg) s0[r] = -3.0e38f;
                    if (kbase + 32 + krow > qg) s1[r] = -3.0e38f;
                }
            }
            float rmax = s0[0];
#pragma unroll
            for (int r = 1; r < 16; ++r) rmax = fmaxf(rmax, s0[r]);
#pragma unroll
            for (int r = 0; r < 16; ++r) rmax = fmaxf(rmax, s1[r]);
            rmax = fmaxf(rmax, __shfl_xor(rmax, 32));
            // defer-max (T13, THR=8)
            if (__any(rmax > m_s + 8.0f)) {
                const float mn = fmaxf(m_s, rmax);
                const float al = exp2f(m_s - mn);
                m_s = mn;
                l_s *= al;
#pragma unroll
                for (int r = 0; r < 16; ++r) {
                    const int qrow = (r & 3) + 8 * (r >> 2) + 4 * hi;
                    const float ar = __shfl(al, qrow);
                    O0[r] *= ar; O1[r] *= ar;
                }
            }
            float rsum = 0.f;
#pragma unroll
            for (int r = 0; r < 16; ++r) { s0[r] = exp2f(s0[r] - m_s); rsum += s0[r]; }
#pragma unroll
            for (int r = 0; r < 16; ++r) { s1[r] = exp2f(s1[r] - m_s); rsum += s1[r]; }
            rsum += __shfl_xor(rsum, 32);
            l_s += rsum;
            // P -> PV A-frags fully in-register (pack pairs, exchange halves via shfl_xor 32)
            bf16x8 pa[4];
#pragma unroll
            for (int kt4 = 0; kt4 < 4; ++kt4) {
                const f32x16& sc = (kt4 < 2) ? s0 : s1;
                const int a8 = (kt4 & 1) * 8;
                const unsigned int plo0 = pk2(sc[a8 + 0], sc[a8 + 1]);
                const unsigned int plo1 = pk2(sc[a8 + 2], sc[a8 + 3]);
                const unsigned int phi0 = pk2(sc[a8 + 4], sc[a8 + 5]);
                const unsigned int phi1 = pk2(sc[a8 + 6], sc[a8 + 7]);
                const unsigned int snd0 = hi ? plo0 : phi0;
                const unsigned int snd1 = hi ? plo1 : phi1;
                const unsigned int r0 = (unsigned int)__shfl_xor((int)snd0, 32);
                const unsigned int r1 = (unsigned int)__shfl_xor((int)snd1, 32);
                union { unsigned int u[4]; bf16x8 v; } fr;
                fr.u[0] = hi ? r0 : plo0;
                fr.u[1] = hi ? r1 : plo1;
                fr.u[2] = hi ? phi0 : r0;
                fr.u[3] = hi ? phi1 : r1;
                pa[kt4] = fr.v;
            }
            // PV: A = P[32q x 16k], B = V[16k x 32d] from V^T LDS rows d
#pragma unroll
            for (int kt4 = 0; kt4 < 4; ++kt4) {
                bf16x8 vf0 = *(const bf16x8*)(Vlb + l31 * 64 + ((kt4 * 16 + hi * 8) ^ swr));
                O0 = __builtin_amdgcn_mfma_f32_32x32x16_bf16(pa[kt4], vf0, O0, 0, 0, 0);
                bf16x8 vf1 = *(const bf16x8*)(Vlb + (32 + l31) * 64 + ((kt4 * 16 + hi * 8) ^ swr));
                O1 = __builtin_amdgcn_mfma_f32_32x32x16_bf16(pa[kt4], vf1, O1, 0, 0, 0);
            }
        }
    }
    const int b = bh >> 4, h = bh & 15;
    const float linv = 1.0f / l_s;
#pragma unroll
    for (int r = 0; r < 16; ++r) {
        const int qrow = (r & 3) + 8 * (r >> 2) + 4 * hi;
        const float iv = __shfl(linv, qrow);
        const size_t ro = ((size_t)b * 2048 + q0w + qrow) * 1024 + (size_t)h * 64;
        y[ro + l31] = __float2bfloat16(O0[r] * iv);
        y[ro + 32 + l31] = __float2bfloat16(O1[r] * iv);
    }
}

extern "C" void kernel_launch(void* const* d_in, const int* in_sizes, int n_in,
                              void* d_out, int out_size, void* d_ws, size_t ws_size,
                              hipStream_t stream) {
    const float* xp = (const float*)d_in[0];
    const float* Wq = (const float*)d_in[1];
    const float* bq = (const float*)d_in[2];
    const float* Wk = (const float*)d_in[3];
    const float* bk = (const float*)d_in[4];
    const float* Wv = (const float*)d_in[5];
    const float* bv = (const float*)d_in[6];
    const float* Wp = (const float*)d_in[7];
    const float* bp = (const float*)d_in[8];
    float* out = (float*)d_out;

    char* ws = (char*)d_ws;
    __hip_bfloat16* xb     = (__hip_bfloat16*)(ws);                  //  4096*1152 bf16
    __hip_bfloat16* Wqkv_t = (__hip_bfloat16*)(ws + 9437184);        //  3072*1152 bf16 (B^T)
    __hip_bfloat16* Wp_t   = (__hip_bfloat16*)(ws + 16515072);       //  1024*1024 bf16 (B^T)
    __hip_bfloat16* qb     = (__hip_bfloat16*)(ws + 18612224);       //  [32][2048][64]
    __hip_bfloat16* kbv    = (__hip_bfloat16*)(ws + 27000832);       //  [32][2048][64]
    __hip_bfloat16* vtb    = (__hip_bfloat16*)(ws + 35389440);       //  [32][64][2048] (V^T)
    __hip_bfloat16* yb     = (__hip_bfloat16*)(ws + 43778048);       //  [4096][1024]

    k_cvt_bf16<<<2304, 256, 0, stream>>>(xp, xb, 589824);
    dim3 trg3(1024 / 32, 1152 / 32, 3);
    k_tr3<<<trg3, 256, 0, stream>>>(Wq, Wk, Wv, Wqkv_t, 1152, 1024);
    dim3 trg2(1024 / 32, 1024 / 32);
    k_tr<<<trg2, 256, 0, stream>>>(Wp, Wp_t, 1024, 1024);

    dim3 g1(4096 / 128, 3072 / 128);
    k_gemm<0><<<g1, 256, 0, stream>>>(xb, Wqkv_t, 4096, 3072, 1152, bq, bk, bv, qb, kbv, vtb, nullptr);
    k_attn<<<512, 256, 0, stream>>>(qb, kbv, vtb, yb);
    dim3 g2(4096 / 128, 1024 / 128);
    k_gemm<1><<<g2, 256, 0, stream>>>(yb, Wp_t, 4096, 1024, 1024, bp, nullptr, nullptr,
                                      nullptr, nullptr, nullptr, out);
}